// Round 12
// baseline (370.029 us; speedup 1.0000x reference)
//
#include <hip/hip_runtime.h>
#include <stdint.h>

typedef int   v4i __attribute__((ext_vector_type(4)));
typedef float v4f __attribute__((ext_vector_type(4)));

// xt layout: [n][hp=58][wp=66][ci=128] int8, zero-padded (hp-1,wp-1 are src coords)
#define XT_H_STRIDE (66*128)          // 8448
#define XT_N_STRIDE (58*66*128)       // 489984
#define XT_BYTES    (32*58*66*128)    // 15,679,488
#define WQ_BYTES    (256*1152)        // 294,912

__device__ __forceinline__ void gload16(const void* g, void* l) {
  __builtin_amdgcn_global_load_lds(
      (const __attribute__((address_space(1))) void*)g,
      (__attribute__((address_space(3))) void*)l, 16, 0, 0);
}

// ---------------- x transform: fp32 NCHW -> int8 [n][hp][wp][ci] ----------------
// Coalesced both sides via LDS transpose. Unchanged (proven, at HBM roofline:
// 67MB moved in ~10.6us).
__global__ __launch_bounds__(256) void xform_x(const float* __restrict__ x,
                                               char* __restrict__ xt) {
  __shared__ int LB[56 * 33];          // [w][32 ci-dwords + 1 pad]
  int bid = blockIdx.x;                // 32*58
  int n  = bid / 58;
  int hp = bid - n * 58;
  int t  = threadIdx.x;
  int srch = hp - 1;
  bool rowok = (srch >= 0) && (srch < 56);
  char* dstrow = xt + (size_t)n * XT_N_STRIDE + (size_t)hp * XT_H_STRIDE;

  if (rowok) {
    const float* rb = x + ((size_t)(n * 128) * 56 + srch) * 56;   // + ci*3136 + w
#pragma unroll
    for (int u0 = 0; u0 < 2; ++u0) {
      int u  = t + u0 * 256;
      int wb = u & 15;
      int cb = u >> 4;
      int w0 = wb * 4, ci0 = cb * 4;
      if (w0 < 56) {
        int dw[4] = {0, 0, 0, 0};
#pragma unroll
        for (int i = 0; i < 4; ++i) {
          v4f f = *(const v4f*)(rb + (size_t)(ci0 + i) * 3136 + w0);
#pragma unroll
          for (int j = 0; j < 4; ++j)
            dw[j] |= (((int)f[j]) & 255) << (8 * i);
        }
#pragma unroll
        for (int j = 0; j < 4; ++j)
          LB[(w0 + j) * 33 + cb] = dw[j];
      }
    }
    __syncthreads();
    for (int c = t; c < 528; c += 256) {
      int wp  = c >> 3;
      int cio = c & 7;
      int srw = wp - 1;
      v4i v = {0, 0, 0, 0};
      if (srw >= 0 && srw < 56) {
#pragma unroll
        for (int k = 0; k < 4; ++k) v[k] = LB[srw * 33 + cio * 4 + k];
      }
      *(v4i*)(dstrow + c * 16) = v;
    }
  } else {
    v4i z = {0, 0, 0, 0};
    for (int c = t; c < 528; c += 256) *(v4i*)(dstrow + c * 16) = z;
  }
}

// ---------------- w transform: OIHW fp32 -> int8 wq4 + scale ----------------
// R15 layout: [kt18][chunk4][co256][16] int8. Per kt the 16KB panel is
// contiguous in exactly DMA-linear order (byte = chunk*4096 + co*16 + col),
// and A-frag ds_reads (chunk = quad, row = wm*64+i*16+l16) are
// lane-contiguous 16B runs (2-way phase aliasing = free).
__global__ __launch_bounds__(256) void xform_w(const float* __restrict__ wsrc,
                                               const int* __restrict__ Aq,
                                               const int* __restrict__ Nq,
                                               char* __restrict__ wq4,
                                               float* __restrict__ scale) {
  int idx = blockIdx.x * 256 + threadIdx.x;    // 294912
  int co = idx / 1152;
  int k  = idx - co * 1152;          // K index: g*128 + ci
  int g  = k >> 7;
  int ci = k & 127;
  int kh = g / 3;
  int kw = g - 3 * kh;
  float f = wsrc[(size_t)(co * 128 + ci) * 9 + kh * 3 + kw];
  int kt    = k >> 6;                // 0..17 (BK=64 window)
  int chunk = (k >> 4) & 3;          // 16B k-chunk within BK=64
  int col   = k & 15;
  wq4[((kt * 4 + chunk) * 256 + co) * 16 + col] = (signed char)(int)f;
  if (idx < 256) {
    scale[idx] = (float)Aq[idx] * exp2f(-(float)Nq[idx]);   // exact: A < 2^15
  }
}

// ---------------- GEMM: C[co][n,h,w] = sum_k wq[co][k] * xt[...] ----------------
// R15: R12's schedule (session-best, 57us) scaled to 512 threads / 256x128
// tile / 24 waves per CU.
//   Ledger: R12 (16 waves, dbuf-LDS, plain frag reads) beats every schedule
//   variant (global-A 60-105, extra-barrier 60-67, fenced 60-66). The only
//   levers that ever moved the number: waves/CU (R8 8w=60 -> R12 16w=57) and
//   per-work staging traffic. Both scale here: all-co block means B slab
//   staged ONCE per spatial tile (was 2x) and A panels shared by 8 waves
//   (was 4) -> ~31% less LDS traffic per work unit; LDS 48KB -> 3 blocks/CU
//   -> 24 waves/CU. Schedule verbatim R12: per window {WAR barrier; DMA
//   next A+B (3 gload16/thread); vmcnt(3); RAW barrier; plain C++ frag reads
//   (compiler-scheduled lgkmcnt) + 16 MFMA}. No setprio/sched_barrier.
// 8 waves as wm=wv&3 (64-co strip) x wn=wv>>2 (64-sp strip); per-wave 4x4
// frags of mfma_i32_16x16x64_i8 (R5/R12-validated mappings, m0==0).
// LDS: As[2][16384] + Bs[2][8192] = 49152. Grid 896 = 8 XCD x 112 (bijective).
__global__ __launch_bounds__(512, 6) void qconv_gemm(
    const char* __restrict__ xt, const char* __restrict__ wq4,
    const float* __restrict__ bias, const float* __restrict__ scale,
    const int* __restrict__ pmin, const int* __restrict__ pmax,
    float* __restrict__ out) {
  __shared__ __align__(16) char As[2][16384];  // [chunk4][co256][16]
  __shared__ __align__(16) char Bs[2][8192];   // [sp128][chunk^(sp&3) 4][16]

  int bid = blockIdx.x;        // 896 = 8 XCD x 112
  int xcd = bid & 7;
  int nt  = xcd * 112 + (bid >> 3);
  int n   = nt / 28;
  int ht  = nt - n * 28;
  int h0  = ht * 2;

  int t  = threadIdx.x;        // 0..511
  int wv = t >> 6;             // 0..7
  int ln = t & 63;
  int quad = ln >> 4;
  int l16  = ln & 15;
  int wm = wv & 3, wn = wv >> 2;

  const char* xb = xt + (size_t)n * XT_N_STRIDE + (size_t)h0 * XT_H_STRIDE;

  // B DMA per-lane source voffset (kt-invariant): slot s = t -> sp = s>>2
  // (dh = sp>>6, w = sp&63), ck = s&3, stored slot = ck^(sp&3).
  int boffv;
  {
    int s  = t;
    int sp = s >> 2;
    int ck = s & 3;
    boffv = (sp >> 6) * XT_H_STRIDE + (sp & 63) * 128 + ((ck ^ (sp & 3)) << 4);
  }
  // frag-read offsets (R12 mappings, m0 = 0)
  const int aoff = quad * 4096 + (wm * 64 + l16) * 16;                 // + i*256
  const int boff = (wn * 64 + l16) * 64 + ((quad ^ (l16 & 3)) << 4);   // + j*1024

  // ---- prologue: DMA kt=0 into buf 0 ----
  {
    const char* a0 = wq4;
    gload16(a0 + t * 16,        As[0] + wv * 1024);
    gload16(a0 + 8192 + t * 16, As[0] + 8192 + wv * 1024);
    gload16(xb + boffv,         Bs[0] + wv * 1024);
  }
  asm volatile("s_waitcnt vmcnt(0)" ::: "memory");
  asm volatile("s_barrier" ::: "memory");

  v4i acc[4][4];
#pragma unroll
  for (int i = 0; i < 4; ++i)
#pragma unroll
    for (int j = 0; j < 4; ++j) {
      v4i z = {0, 0, 0, 0};
      acc[i][j] = z;
    }

#pragma unroll
  for (int kt = 0; kt < 18; ++kt) {
    const int buf = kt & 1;

    // all waves finished reading buf^1 (in kt-1) -> safe to DMA-overwrite it
    asm volatile("s_barrier" ::: "memory");
    if (kt < 17) {
      const int kn  = kt + 1;
      const int gn  = kn >> 1;
      const int pn  = kn & 1;
      const int khn = gn / 3;
      const int kwn = gn - 3 * khn;
      const int koff = khn * XT_H_STRIDE + kwn * 128 + pn * 64;  // uniform
      const char* an = wq4 + (size_t)kn * 16384;
      gload16(an + t * 16,        As[buf ^ 1] + wv * 1024);
      gload16(an + 8192 + t * 16, As[buf ^ 1] + 8192 + wv * 1024);
      gload16(xb + koff + boffv,  Bs[buf ^ 1] + wv * 1024);
      asm volatile("s_waitcnt vmcnt(3)" ::: "memory");  // current buf's 3 landed
    } else {
      asm volatile("s_waitcnt vmcnt(0)" ::: "memory");
    }
    asm volatile("s_barrier" ::: "memory");             // cross-wave: buf ready

    // frag reads: plain C++ -> compiler emits fine-grained lgkmcnt (m97).
    v4i a[4], b[4];
#pragma unroll
    for (int i = 0; i < 4; ++i)
      a[i] = *(const v4i*)(As[buf] + aoff + i * 256);
#pragma unroll
    for (int j = 0; j < 4; ++j)
      b[j] = *(const v4i*)(Bs[buf] + boff + j * 1024);
#pragma unroll
    for (int i = 0; i < 4; ++i)
#pragma unroll
      for (int j = 0; j < 4; ++j)
        acc[i][j] = __builtin_amdgcn_mfma_i32_16x16x64_i8(a[i], b[j], acc[i][j], 0, 0, 0);
  }

  // epilogue (R5/R12-validated): co = wm*64 + i*16 + quad*4 + r ;
  // spatial sl = wn*64 + j*16 + l16 -> w = sl&63, dh = sl>>6 (== wn)
  float mn = (float)pmin[0];
  float mx = (float)pmax[0];
#pragma unroll
  for (int i = 0; i < 4; ++i) {
    int co_b = wm * 64 + i * 16 + quad * 4;
    v4f bs4 = *(const v4f*)(bias + co_b);
    v4f sc4 = *(const v4f*)(scale + co_b);
#pragma unroll
    for (int r = 0; r < 4; ++r) {
      int co = co_b + r;
      float bs = bs4[r];
      float sc = sc4[r];
#pragma unroll
      for (int j = 0; j < 4; ++j) {
        int sl = wn * 64 + j * 16 + l16;
        int w  = sl & 63;
        int dh = sl >> 6;
        if (w < 56) {
          float f = (float)acc[i][j][r] + bs;
          f = rintf(f * sc);                 // half-to-even, matches np.round
          f = fminf(fmaxf(f, mn), mx);
          out[(((size_t)n * 256 + co) * 56 + (h0 + dh)) * 56 + w] = f;
        }
      }
    }
  }
}

extern "C" void kernel_launch(void* const* d_in, const int* in_sizes, int n_in,
                              void* d_out, int out_size, void* d_ws, size_t ws_size,
                              hipStream_t stream) {
  const float* x  = (const float*)d_in[0];
  const float* w  = (const float*)d_in[1];
  const float* b  = (const float*)d_in[2];
  const int*   Aq = (const int*)d_in[3];
  const int*   Nq = (const int*)d_in[4];
  const int*   mn = (const int*)d_in[5];
  const int*   mx = (const int*)d_in[6];
  float* out = (float*)d_out;

  char*  xt    = (char*)d_ws;                  // 15,679,488 B
  char*  wq4   = xt + XT_BYTES;                // 294,912 B (kt/chunk/co256 layout)
  float* scale = (float*)(wq4 + WQ_BYTES);     // 1 KiB

  hipLaunchKernelGGL(xform_x, dim3(32 * 58), dim3(256), 0, stream, x, xt);
  hipLaunchKernelGGL(xform_w, dim3(1152), dim3(256), 0, stream, w, Aq, Nq, wq4, scale);
  hipLaunchKernelGGL(qconv_gemm, dim3(896), dim3(512), 0, stream,
                     xt, wq4, b, scale, mn, mx, out);
}

// Round 13
// 187.855 us; speedup vs baseline: 1.9698x; 1.9698x over previous
//
#include <hip/hip_runtime.h>
#include <stdint.h>

typedef int   v4i __attribute__((ext_vector_type(4)));
typedef float v4f __attribute__((ext_vector_type(4)));

// xt layout: [n][hp=58][wp=66][ci=128] int8, zero-padded (hp-1,wp-1 are src coords)
#define XT_H_STRIDE (66*128)          // 8448
#define XT_N_STRIDE (58*66*128)       // 489984
#define XT_BYTES    (32*58*66*128)    // 15,679,488
#define WQ_BYTES    (256*1152)        // 294,912

__device__ __forceinline__ void gload16(const void* g, void* l) {
  __builtin_amdgcn_global_load_lds(
      (const __attribute__((address_space(1))) void*)g,
      (__attribute__((address_space(3))) void*)l, 16, 0, 0);
}

// ---------------- x transform: fp32 NCHW -> int8 [n][hp][wp][ci] ----------------
// Coalesced both sides via LDS transpose. Unchanged (proven, HBM roofline).
__global__ __launch_bounds__(256) void xform_x(const float* __restrict__ x,
                                               char* __restrict__ xt) {
  __shared__ int LB[56 * 33];          // [w][32 ci-dwords + 1 pad]
  int bid = blockIdx.x;                // 32*58
  int n  = bid / 58;
  int hp = bid - n * 58;
  int t  = threadIdx.x;
  int srch = hp - 1;
  bool rowok = (srch >= 0) && (srch < 56);
  char* dstrow = xt + (size_t)n * XT_N_STRIDE + (size_t)hp * XT_H_STRIDE;

  if (rowok) {
    const float* rb = x + ((size_t)(n * 128) * 56 + srch) * 56;   // + ci*3136 + w
#pragma unroll
    for (int u0 = 0; u0 < 2; ++u0) {
      int u  = t + u0 * 256;
      int wb = u & 15;
      int cb = u >> 4;
      int w0 = wb * 4, ci0 = cb * 4;
      if (w0 < 56) {
        int dw[4] = {0, 0, 0, 0};
#pragma unroll
        for (int i = 0; i < 4; ++i) {
          v4f f = *(const v4f*)(rb + (size_t)(ci0 + i) * 3136 + w0);
#pragma unroll
          for (int j = 0; j < 4; ++j)
            dw[j] |= (((int)f[j]) & 255) << (8 * i);
        }
#pragma unroll
        for (int j = 0; j < 4; ++j)
          LB[(w0 + j) * 33 + cb] = dw[j];
      }
    }
    __syncthreads();
    for (int c = t; c < 528; c += 256) {
      int wp  = c >> 3;
      int cio = c & 7;
      int srw = wp - 1;
      v4i v = {0, 0, 0, 0};
      if (srw >= 0 && srw < 56) {
#pragma unroll
        for (int k = 0; k < 4; ++k) v[k] = LB[srw * 33 + cio * 4 + k];
      }
      *(v4i*)(dstrow + c * 16) = v;
    }
  } else {
    v4i z = {0, 0, 0, 0};
    for (int c = t; c < 528; c += 256) *(v4i*)(dstrow + c * 16) = z;
  }
}

// ---------------- w transform: OIHW fp32 -> int8 wq4 + scale ----------------
// R15 layout (kept): [kt18][chunk4][co256][16] int8. Per (kt, chunk, co-half)
// the 2KB co-run is contiguous -> the GEMM's per-thread A-DMA is one coalesced
// gload16; A-frag ds_reads are lane-contiguous (2-way aliasing = free).
__global__ __launch_bounds__(256) void xform_w(const float* __restrict__ wsrc,
                                               const int* __restrict__ Aq,
                                               const int* __restrict__ Nq,
                                               char* __restrict__ wq4,
                                               float* __restrict__ scale) {
  int idx = blockIdx.x * 256 + threadIdx.x;    // 294912
  int co = idx / 1152;
  int k  = idx - co * 1152;          // K index: g*128 + ci
  int g  = k >> 7;
  int ci = k & 127;
  int kh = g / 3;
  int kw = g - 3 * kh;
  float f = wsrc[(size_t)(co * 128 + ci) * 9 + kh * 3 + kw];
  int kt    = k >> 6;                // 0..17 (BK=64 window)
  int chunk = (k >> 4) & 3;          // 16B k-chunk within BK=64
  int col   = k & 15;
  wq4[((kt * 4 + chunk) * 256 + co) * 16 + col] = (signed char)(int)f;
  if (idx < 256) {
    scale[idx] = (float)Aq[idx] * exp2f(-(float)Nq[idx]);   // exact: A < 2^15
  }
}

// ---------------- GEMM: C[co][n,h,w] = sum_k wq[co][k] * xt[...] ----------------
// R16: R12's schedule (session-best) with HALVED A-traffic via a 128co x 256sp
// block (8 waves), correct register budget this time.
//   R15 post-mortem: __launch_bounds__(512,6) capped VGPR at ~85 < acc(64)+frags
//   -> acc spilled to scratch (VGPR=40, FETCH 224MB, 221us). Occupancy >16
//   waves/CU is unreachable with a 64-VGPR acc; lever closed.
//   Surviving lever: skinny-M A re-staging. M=256 means every block DMAs all
//   288KB of weights; R12's 1792 blocks move 516MB of A through L2+LDS (2x the
//   B traffic, ~15us aggregate L2 time in the window critical path). 256sp per
//   block -> 896 blocks -> A traffic halves; B traffic unchanged. Schedule,
//   per-wave frag pattern (4+4 b128 reads, 16 MFMA), 2-barrier window,
//   vmcnt(3), 16 waves/CU: all verbatim R12.
// 8 waves: wm = wv&1 (64-co strip), wn = wv>>1 (64-sp strip, = dh row).
// LDS: As[2][8192] ([chunk4][co128][16]) + Bs[2][16384] = 49152 -> 2 blk/CU.
// __launch_bounds__(512,4): VGPR cap 128 (est ~116, no spill).
// Grid 896 = 8 XCD x 112, mt in LSB so co-halves of one tile pair per XCD.
__global__ __launch_bounds__(512, 4) void qconv_gemm(
    const char* __restrict__ xt, const char* __restrict__ wq4,
    const float* __restrict__ bias, const float* __restrict__ scale,
    const int* __restrict__ pmin, const int* __restrict__ pmax,
    float* __restrict__ out) {
  __shared__ __align__(16) char As[2][8192];   // [chunk4][co128][16]
  __shared__ __align__(16) char Bs[2][16384];  // [sp256][slot4][16], slot=ck^(sp&3)

  int bid = blockIdx.x;        // 896 = 8 XCD x 112
  int xcd = bid & 7;
  int gq  = xcd * 112 + (bid >> 3);   // 0..895, contiguous run per XCD
  int mt  = gq & 1;
  int nt  = gq >> 1;           // 0..447
  int n   = nt / 14;
  int ht  = nt - n * 14;
  int h0  = ht * 4;            // 4 output rows per block
  int m0  = mt * 128;

  int t  = threadIdx.x;        // 0..511
  int wv = t >> 6;             // 0..7
  int ln = t & 63;
  int quad = ln >> 4;
  int l16  = ln & 15;
  int wm = wv & 1, wn = wv >> 1;   // wn 0..3 = dh row

  const char* xb = xt + (size_t)n * XT_N_STRIDE + (size_t)h0 * XT_H_STRIDE;

  // A DMA source (kt-invariant tail): thread t stages dest byte t*16 of the
  // 8KB panel [chunk=t>>7][co=t&127]; src run is 2KB-contiguous.
  const int asrc_off = (t >> 7) * 4096 + mt * 2048 + (t & 127) * 16;
  // B DMA source voffsets (kt-invariant): pass p slot s = t + p*512;
  // sp = s>>2 (dh = sp>>6, w = sp&63), stored slot s&3 holds ck = (s&3)^(sp&3).
  int boffv[2];
#pragma unroll
  for (int p = 0; p < 2; ++p) {
    int s  = t + p * 512;
    int sp = s >> 2;
    boffv[p] = (sp >> 6) * XT_H_STRIDE + (sp & 63) * 128 + (((s & 3) ^ (sp & 3)) << 4);
  }
  // frag-read offsets (R12-validated mappings)
  const int aoff = quad * 2048 + (wm * 64 + l16) * 16;                 // + i*256
  const int boff = (wn * 64 + l16) * 64 + ((quad ^ (l16 & 3)) << 4);   // + j*1024

  // ---- prologue: DMA kt=0 into buf 0 ----
  gload16(wq4 + asrc_off,     As[0] + wv * 1024);
  gload16(xb + boffv[0],      Bs[0] + wv * 1024);
  gload16(xb + boffv[1],      Bs[0] + 8192 + wv * 1024);
  asm volatile("s_waitcnt vmcnt(0)" ::: "memory");
  asm volatile("s_barrier" ::: "memory");

  v4i acc[4][4];
#pragma unroll
  for (int i = 0; i < 4; ++i)
#pragma unroll
    for (int j = 0; j < 4; ++j) {
      v4i z = {0, 0, 0, 0};
      acc[i][j] = z;
    }

#pragma unroll
  for (int kt = 0; kt < 18; ++kt) {
    const int buf = kt & 1;

    // all waves finished reading buf^1 (in kt-1) -> safe to DMA-overwrite it
    asm volatile("s_barrier" ::: "memory");
    if (kt < 17) {
      const int kn  = kt + 1;
      const int gn  = kn >> 1;
      const int pn  = kn & 1;
      const int khn = gn / 3;
      const int kwn = gn - 3 * khn;
      const int koff = khn * XT_H_STRIDE + kwn * 128 + pn * 64;  // uniform
      gload16(wq4 + kn * 16384 + asrc_off, As[buf ^ 1] + wv * 1024);
      gload16(xb + koff + boffv[0],        Bs[buf ^ 1] + wv * 1024);
      gload16(xb + koff + boffv[1],        Bs[buf ^ 1] + 8192 + wv * 1024);
      asm volatile("s_waitcnt vmcnt(3)" ::: "memory");  // current buf's 3 landed
    } else {
      asm volatile("s_waitcnt vmcnt(0)" ::: "memory");
    }
    asm volatile("s_barrier" ::: "memory");             // cross-wave: buf ready

    // frag reads: plain C++ -> compiler emits fine-grained lgkmcnt (m97).
    v4i a[4], b[4];
#pragma unroll
    for (int i = 0; i < 4; ++i)
      a[i] = *(const v4i*)(As[buf] + aoff + i * 256);
#pragma unroll
    for (int j = 0; j < 4; ++j)
      b[j] = *(const v4i*)(Bs[buf] + boff + j * 1024);
#pragma unroll
    for (int i = 0; i < 4; ++i)
#pragma unroll
      for (int j = 0; j < 4; ++j)
        acc[i][j] = __builtin_amdgcn_mfma_i32_16x16x64_i8(a[i], b[j], acc[i][j], 0, 0, 0);
  }

  // epilogue (R12-validated): co = m0 + wm*64 + i*16 + quad*4 + r ;
  // spatial sl = wn*64 + j*16 + l16 -> w = j*16+l16 (<64), dh = wn
  float mn = (float)pmin[0];
  float mx = (float)pmax[0];
#pragma unroll
  for (int i = 0; i < 4; ++i) {
    int co_b = m0 + wm * 64 + i * 16 + quad * 4;
    v4f bs4 = *(const v4f*)(bias + co_b);
    v4f sc4 = *(const v4f*)(scale + co_b);
#pragma unroll
    for (int r = 0; r < 4; ++r) {
      int co = co_b + r;
      float bs = bs4[r];
      float sc = sc4[r];
      size_t obase = (((size_t)n * 256 + co) * 56 + (h0 + wn)) * 56;
#pragma unroll
      for (int j = 0; j < 4; ++j) {
        int w = j * 16 + l16;
        if (w < 56) {
          float f = (float)acc[i][j][r] + bs;
          f = rintf(f * sc);                 // half-to-even, matches np.round
          f = fminf(fmaxf(f, mn), mx);
          out[obase + w] = f;
        }
      }
    }
  }
}

extern "C" void kernel_launch(void* const* d_in, const int* in_sizes, int n_in,
                              void* d_out, int out_size, void* d_ws, size_t ws_size,
                              hipStream_t stream) {
  const float* x  = (const float*)d_in[0];
  const float* w  = (const float*)d_in[1];
  const float* b  = (const float*)d_in[2];
  const int*   Aq = (const int*)d_in[3];
  const int*   Nq = (const int*)d_in[4];
  const int*   mn = (const int*)d_in[5];
  const int*   mx = (const int*)d_in[6];
  float* out = (float*)d_out;

  char*  xt    = (char*)d_ws;                  // 15,679,488 B
  char*  wq4   = xt + XT_BYTES;                // 294,912 B (kt/chunk/co256 layout)
  float* scale = (float*)(wq4 + WQ_BYTES);     // 1 KiB

  hipLaunchKernelGGL(xform_x, dim3(32 * 58), dim3(256), 0, stream, x, xt);
  hipLaunchKernelGGL(xform_w, dim3(1152), dim3(256), 0, stream, w, Aq, Nq, wq4, scale);
  hipLaunchKernelGGL(qconv_gemm, dim3(896), dim3(512), 0, stream,
                     xt, wq4, b, scale, mn, mx, out);
}